// Round 12
// baseline (258.397 us; speedup 1.0000x reference)
//
#include <hip/hip_runtime.h>
#include <hip/hip_bf16.h>

// RBF-KAN as one fused bf16 MFMA GEMM:
//   out[b,o] = sum_k A[b,k] * W[k,o] + bias[o]
//   k = ic*832 + slot*64 + ii, i = ic*64+ii
//   slot==0: A = x[b,i];  slot>=1: A = basis(x[b,i], g=slot-1)
// basis recurrence with u = x*1.375 + 5.5:
//   bb_0 = exp(-u^2/2); bb_{g+1} = bb_g*ff_g; ff_0 = exp(u-0.5); ff_{g+1} = ff_g*e^-1
//
// Round 12: r11 (B direct-from-global with 1-step register prefetch, lgkm-only
// barrier, compiler scheduling) + PAIR-STEP: two K-steps per barrier. A dbuf
// holds 2 steps (2x32KB); per iter: {loadB(t+2) | readA(t) | emit A(t+2) |
// MFMA(t) | loadB(t+3) | readA(t+1) | emit A(t+3) | MFMA(t+1) | lgkm+barrier}.
// 52 barriers instead of 104; 2x compiler scheduling window. 4 named B reg
// sets, loads staggered so <=3 live. No sched_barrier/setprio/manual vmcnt.

#define N_DIM 512
#define I_DIM 512
#define KTOT  6656
#define NSTEP 104      // 104 K-steps of 64 = 8 chunks x 13 slots
#define NPAIR 52

typedef short short8 __attribute__((ext_vector_type(8)));
typedef float f32x16 __attribute__((ext_vector_type(16)));
typedef unsigned int u32x4 __attribute__((ext_vector_type(4)));

#define CVTPK(dst, lo, hi) \
  asm("v_cvt_pk_bf16_f32 %0, %1, %2" : "=v"(dst) : "v"(lo), "v"(hi))

__device__ __forceinline__ unsigned short f2bf(float f) {
  union { float f; unsigned int u; } c; c.f = f;
  unsigned int r = (c.u + 0x7FFFu + ((c.u >> 16) & 1)) >> 16;  // RNE, finite only
  return (unsigned short)r;
}

// ---------------- prep: repack coeff + base_w into bf16 Wb2[g][o][e] ----------------
// g = k >> 3 (16B k-granule, 0..831), e = k & 7.
__global__ __launch_bounds__(256) void prep_w(const float* __restrict__ coeff,
                                              const float* __restrict__ base_w,
                                              unsigned short* __restrict__ Wb2) {
  int t = blockIdx.x * 256 + threadIdx.x;   // 851968 threads, 4 shorts each
  int e0 = (t & 1) * 4;
  int go = t >> 1;                          // g*512 + o
  int o  = go & 511;
  int g  = go >> 9;
  int k4 = g * 8 + e0;
  int ic = k4 / 832;
  int rem = k4 - ic * 832;
  int slot = rem >> 6;
  int ii = rem & 63;
  int i = ic * 64 + ii;
  float v0, v1, v2, v3;
  if (slot == 0) {
    const float4 bw = *(const float4*)(base_w + (size_t)o * I_DIM + i);
    v0 = bw.x; v1 = bw.y; v2 = bw.z; v3 = bw.w;
  } else {
    int gg = slot - 1;
    const float* cp = coeff + (size_t)i * (N_DIM * 12) + o * 12 + gg;
    v0 = cp[0]; v1 = cp[6144]; v2 = cp[2 * 6144]; v3 = cp[3 * 6144];
  }
  ushort4 s;
  s.x = f2bf(v0); s.y = f2bf(v1); s.z = f2bf(v2); s.w = f2bf(v3);
  *(ushort4*)(Wb2 + (size_t)go * 8 + e0) = s;
}

// ---------------- main fused GEMM ----------------
__global__ __launch_bounds__(512, 2) void kan_gemm(const float* __restrict__ x,
                                                   const unsigned short* __restrict__ Wb2,
                                                   const float* __restrict__ bias,
                                                   float* __restrict__ out) {
  // A double-buffer, 2 K-steps per buffer: [2][st 2][kg 8][row 128][8] = 64 KB
  __shared__ unsigned short Asw[2][2 * 8 * 128 * 8];

  const int tid  = threadIdx.x;
  const int lane = tid & 63;
  const int wid  = tid >> 6;                  // 8 waves: 2(wm) x 4(wn)
  const int wm   = wid >> 2, wn = wid & 3;    // wave tile 64x64
  const int l31  = lane & 31, hl = lane >> 5;

  // XCD decode: XCDs 0-3 -> cb=0, XCDs 4-7 -> cb=1 (W col-panel per L2)
  const int bid = blockIdx.x;                 // grid 256
  const int xcd = bid & 7, jj = bid >> 3;     // jj 0..31
  const int cb  = xcd >> 2;
  const int rb  = jj * 4 + (xcd & 3);         // 0..127
  const int M0  = rb * 128;
  const int N0  = cb * 256;

  // ---- A staging map: thread -> (row arow, granule pair kgp), 16 elems ----
  const int arow = tid & 127;
  const int kgp  = tid >> 7;                  // granules 2kgp, 2kgp+1
  const float* xg = x + (size_t)(M0 + arow) * I_DIM + kgp * 16;
  const int aoff0 = ((kgp * 2) * 128 + arow) * 16;      // bytes (within st block)
  const int aoff1 = ((kgp * 2 + 1) * 128 + arow) * 16;

  // ---- B direct-global per-lane byte offsets (within one K-step = 64KB) ----
  const char* Wb = (const char*)Wb2;
  int boff[4][2];
#pragma unroll
  for (int s = 0; s < 4; ++s)
#pragma unroll
    for (int fo = 0; fo < 2; ++fo)
      boff[s][fo] = (((s * 2 + hl) * 512) + N0 + wn * 64 + fo * 32 + l31) * 16;

  // ---- A compute-side byte base (within st block) ----
  const int aBase = (hl * 128 + wm * 64 + l31) * 16;   // + s*4096 (+512 fb=1)

  f32x16 acc[2][2];
#pragma unroll
  for (int i = 0; i < 2; ++i)
#pragma unroll
    for (int j = 0; j < 2; ++j)
#pragma unroll
      for (int r = 0; r < 16; ++r) acc[i][j][r] = 0.f;

  // ---- A-gen state ----
  float bb[16], ff[16];
  float4 xh[4];
  int eslot = 0, cchunk = 0;                  // eslot = slot of NEXT emit target
#pragma unroll
  for (int q = 0; q < 4; ++q) xh[q] = *(const float4*)(xg + q * 4);   // chunk 0

  auto loadB = [&](short8 (&bv)[4][2], int tt) {
    const char* WbT = Wb + (size_t)tt * 65536;
#pragma unroll
    for (int s = 0; s < 4; ++s) {
      bv[s][0] = *(const short8*)(WbT + boff[s][0]);
      bv[s][1] = *(const short8*)(WbT + boff[s][1]);
    }
  };

  // emit one K-step's A slice into pDst (st offset included by caller)
  auto emitA = [&](char* pDst) {
    unsigned int w[8];
    if (eslot == 0) {                         // A = x (current chunk), init basis
      float f[16];
#pragma unroll
      for (int q = 0; q < 4; ++q) {
        f[q*4+0] = xh[q].x; f[q*4+1] = xh[q].y; f[q*4+2] = xh[q].z; f[q*4+3] = xh[q].w;
      }
#pragma unroll
      for (int j = 0; j < 8; ++j) CVTPK(w[j], f[2*j], f[2*j+1]);
      *(u32x4*)(pDst + aoff0) = (u32x4){w[0], w[1], w[2], w[3]};
      *(u32x4*)(pDst + aoff1) = (u32x4){w[4], w[5], w[6], w[7]};
#pragma unroll
      for (int j = 0; j < 16; ++j) {
        float u = fmaf(f[j], 1.375f, 5.5f);
        bb[j] = exp2f(-0.72134752044448170f * u * u);
        ff[j] = exp2f(fmaf(u, 1.44269504088896340f, -0.72134752044448170f));
      }
    } else {                                  // A = basis, advance recurrence
#pragma unroll
      for (int j = 0; j < 8; ++j) CVTPK(w[j], bb[2*j], bb[2*j+1]);
      *(u32x4*)(pDst + aoff0) = (u32x4){w[0], w[1], w[2], w[3]};
      *(u32x4*)(pDst + aoff1) = (u32x4){w[4], w[5], w[6], w[7]};
#pragma unroll
      for (int j = 0; j < 16; ++j) {
        bb[j] *= ff[j];
        ff[j] *= 0.36787944117144233f;        // e^-1
      }
    }
    if (eslot == 1 && cchunk < 7) {           // preload next x chunk (~12 steps early)
      ++cchunk;
      const float* xn = xg + (size_t)cchunk * 64;
#pragma unroll
      for (int q = 0; q < 4; ++q) xh[q] = *(const float4*)(xn + q * 4);
    }
    eslot = (eslot == 12) ? 0 : eslot + 1;
  };

#define MFMA_CLUSTER(AV, BV)                                                         \
  _Pragma("unroll")                                                                  \
  for (int s = 0; s < 4; ++s) {                                                      \
    acc[0][0] = __builtin_amdgcn_mfma_f32_32x32x16_bf16(AV[s][0], BV[s][0], acc[0][0], 0, 0, 0); \
    acc[0][1] = __builtin_amdgcn_mfma_f32_32x32x16_bf16(AV[s][0], BV[s][1], acc[0][1], 0, 0, 0); \
    acc[1][0] = __builtin_amdgcn_mfma_f32_32x32x16_bf16(AV[s][1], BV[s][0], acc[1][0], 0, 0, 0); \
    acc[1][1] = __builtin_amdgcn_mfma_f32_32x32x16_bf16(AV[s][1], BV[s][1], acc[1][1], 0, 0, 0); \
  }

  // one pair of K-steps (t0 = 2p, t1 = 2p+1); abuf = p&1
  auto pairBody = [&](int p, int abuf, short8 (&bc0)[4][2], short8 (&bc1)[4][2],
                      short8 (&bn0)[4][2], short8 (&bn1)[4][2]) {
    const int t0 = 2 * p;
    const bool more = (t0 + 2 < NSTEP);       // p <= 50
    const char* pA  = (const char*)&Asw[abuf][0];
    char*       pAe = (char*)&Asw[abuf ^ 1][0];

    if (more) loadB(bn0, t0 + 2);
    short8 av[4][2];
#pragma unroll
    for (int s = 0; s < 4; ++s) {
      av[s][0] = *(const short8*)(pA + aBase + s * 4096);
      av[s][1] = *(const short8*)(pA + aBase + s * 4096 + 512);
    }
    if (more) emitA(pAe);                     // target t0+2 (st 0)
    MFMA_CLUSTER(av, bc0);

    if (more) loadB(bn1, t0 + 3);
#pragma unroll
    for (int s = 0; s < 4; ++s) {
      av[s][0] = *(const short8*)(pA + 16384 + aBase + s * 4096);
      av[s][1] = *(const short8*)(pA + 16384 + aBase + s * 4096 + 512);
    }
    if (more) emitA(pAe + 16384);             // target t0+3 (st 1)
    MFMA_CLUSTER(av, bc1);

    // lgkm-only barrier: A ds_writes drained; this wave's ds_reads already
    // consumed by MFMA. B prefetch loads stay in flight across the barrier.
    asm volatile("s_waitcnt lgkmcnt(0)" ::: "memory");
    __builtin_amdgcn_s_barrier();
  };

  // ================= prologue: emit A(0),A(1); load B(0),B(1) =================
  short8 bvA[4][2], bvB[4][2], bvC[4][2], bvD[4][2];
  emitA((char*)&Asw[0][0]);                   // A(0), st 0 (slot 0: inits bb/ff)
  emitA((char*)&Asw[0][0] + 16384);           // A(1), st 1 (slot 1)
  loadB(bvA, 0);
  loadB(bvB, 1);
  asm volatile("s_waitcnt lgkmcnt(0)" ::: "memory");
  __builtin_amdgcn_s_barrier();

  // ================= main loop: 2 pairs/iter, named reg-set rotation =================
#pragma unroll 1
  for (int p = 0; p < NPAIR; p += 2) {
    pairBody(p,     0, bvA, bvB, bvC, bvD);
    pairBody(p + 1, 1, bvC, bvD, bvA, bvB);
  }

  // ---- epilogue: D col(o) = lane&31, row(b) = (r&3)+8*(r>>2)+4*hl ----
  float bvv[2];
#pragma unroll
  for (int fo = 0; fo < 2; ++fo) bvv[fo] = bias[N0 + wn * 64 + fo * 32 + l31];
  const int rbase = 4 * hl;
#pragma unroll
  for (int fb = 0; fb < 2; ++fb) {
#pragma unroll
    for (int fo = 0; fo < 2; ++fo) {
      const size_t cix = (size_t)(N0 + wn * 64 + fo * 32 + l31);
#pragma unroll
      for (int r = 0; r < 16; ++r) {
        int row = M0 + wm * 64 + fb * 32 + (r & 3) + 8 * (r >> 2) + rbase;
        out[(size_t)row * N_DIM + cix] = acc[fb][fo][r] + bvv[fo];
      }
    }
  }
}

extern "C" void kernel_launch(void* const* d_in, const int* in_sizes, int n_in,
                              void* d_out, int out_size, void* d_ws, size_t ws_size,
                              hipStream_t stream) {
  const float* x      = (const float*)d_in[0];
  const float* coeff  = (const float*)d_in[1];
  const float* base_w = (const float*)d_in[2];
  const float* base_b = (const float*)d_in[3];
  // d_in[4] (centers) is implied by u = x*1.375 + 5.5 (exact)
  unsigned short* Wb2 = (unsigned short*)d_ws;   // needs 6,815,744 B

  prep_w<<<3328, 256, 0, stream>>>(coeff, base_w, Wb2);
  kan_gemm<<<256, 512, 0, stream>>>(x, Wb2, base_b, (float*)d_out);
}

// Round 13
// 132.341 us; speedup vs baseline: 1.9525x; 1.9525x over previous
//
#include <hip/hip_runtime.h>
#include <hip/hip_bf16.h>

// RBF-KAN as one fused bf16 MFMA GEMM:
//   out[b,o] = sum_k A[b,k] * W[k,o] + bias[o]
//   k = ic*832 + slot*64 + ii, i = ic*64+ii
//   slot==0: A = x[b,i];  slot>=1: A = basis(x[b,i], g=slot-1)
// basis recurrence with u = x*1.375 + 5.5:
//   bb_0 = exp(-u^2/2); bb_{g+1} = bb_g*ff_g; ff_0 = exp(u-0.5); ff_{g+1} = ff_g*e^-1
//
// Round 13: r11 mechanics (B direct-from-global, 1-step reg prefetch with TWO
// named B sets, lgkm-only raw barrier, compiler scheduling) + A-LDS 4-ring
// with emit 2 STEPS AHEAD -> barrier every 2 steps (52 total). Within a
// barrier window the 2nd step's A-slot is already protected (written t-2),
// so the compiler can slide its reads/loads under the 1st MFMA cluster.
// Hazards: RAW emit(t)->read(t+2) spans 1 barrier; WAR write slot (t+2)%4
// vs last read at t-2 spans the previous window's barrier.

#define N_DIM 512
#define I_DIM 512
#define KTOT  6656
#define NSTEP 104      // 104 K-steps of 64 = 8 chunks x 13 slots

typedef short short8 __attribute__((ext_vector_type(8)));
typedef float f32x16 __attribute__((ext_vector_type(16)));
typedef unsigned int u32x4 __attribute__((ext_vector_type(4)));

#define CVTPK(dst, lo, hi) \
  asm("v_cvt_pk_bf16_f32 %0, %1, %2" : "=v"(dst) : "v"(lo), "v"(hi))

__device__ __forceinline__ unsigned short f2bf(float f) {
  union { float f; unsigned int u; } c; c.f = f;
  unsigned int r = (c.u + 0x7FFFu + ((c.u >> 16) & 1)) >> 16;  // RNE, finite only
  return (unsigned short)r;
}

// ---------------- prep: repack coeff + base_w into bf16 Wb2[g][o][e] ----------------
// g = k >> 3 (16B k-granule, 0..831), e = k & 7.
__global__ __launch_bounds__(256) void prep_w(const float* __restrict__ coeff,
                                              const float* __restrict__ base_w,
                                              unsigned short* __restrict__ Wb2) {
  int t = blockIdx.x * 256 + threadIdx.x;   // 851968 threads, 4 shorts each
  int e0 = (t & 1) * 4;
  int go = t >> 1;                          // g*512 + o
  int o  = go & 511;
  int g  = go >> 9;
  int k4 = g * 8 + e0;
  int ic = k4 / 832;
  int rem = k4 - ic * 832;
  int slot = rem >> 6;
  int ii = rem & 63;
  int i = ic * 64 + ii;
  float v0, v1, v2, v3;
  if (slot == 0) {
    const float4 bw = *(const float4*)(base_w + (size_t)o * I_DIM + i);
    v0 = bw.x; v1 = bw.y; v2 = bw.z; v3 = bw.w;
  } else {
    int gg = slot - 1;
    const float* cp = coeff + (size_t)i * (N_DIM * 12) + o * 12 + gg;
    v0 = cp[0]; v1 = cp[6144]; v2 = cp[2 * 6144]; v3 = cp[3 * 6144];
  }
  ushort4 s;
  s.x = f2bf(v0); s.y = f2bf(v1); s.z = f2bf(v2); s.w = f2bf(v3);
  *(ushort4*)(Wb2 + (size_t)go * 8 + e0) = s;
}

// ---------------- main fused GEMM ----------------
__global__ __launch_bounds__(512, 2) void kan_gemm(const float* __restrict__ x,
                                                   const unsigned short* __restrict__ Wb2,
                                                   const float* __restrict__ bias,
                                                   float* __restrict__ out) {
  // A ring, 4 deep: [4][kg 8][row 128][8 bf16] = 64 KB (slot = t % 4)
  __shared__ unsigned short Asw[4 * 8 * 128 * 8];

  const int tid  = threadIdx.x;
  const int lane = tid & 63;
  const int wid  = tid >> 6;                  // 8 waves: 2(wm) x 4(wn)
  const int wm   = wid >> 2, wn = wid & 3;    // wave tile 64x64
  const int l31  = lane & 31, hl = lane >> 5;

  // XCD decode: XCDs 0-3 -> cb=0, XCDs 4-7 -> cb=1 (W col-panel per L2)
  const int bid = blockIdx.x;                 // grid 256
  const int xcd = bid & 7, jj = bid >> 3;     // jj 0..31
  const int cb  = xcd >> 2;
  const int rb  = jj * 4 + (xcd & 3);         // 0..127
  const int M0  = rb * 128;
  const int N0  = cb * 256;

  // ---- A staging map: thread -> (row arow, granule pair kgp), 16 elems ----
  const int arow = tid & 127;
  const int kgp  = tid >> 7;                  // granules 2kgp, 2kgp+1
  const float* xg = x + (size_t)(M0 + arow) * I_DIM + kgp * 16;
  const int aoff0 = ((kgp * 2) * 128 + arow) * 16;      // bytes (within slot)
  const int aoff1 = ((kgp * 2 + 1) * 128 + arow) * 16;

  // ---- B direct-global per-lane byte offsets (within one K-step = 64KB) ----
  const char* Wb = (const char*)Wb2;
  int boff[4][2];
#pragma unroll
  for (int s = 0; s < 4; ++s)
#pragma unroll
    for (int fo = 0; fo < 2; ++fo)
      boff[s][fo] = (((s * 2 + hl) * 512) + N0 + wn * 64 + fo * 32 + l31) * 16;

  // ---- A compute-side byte base (within slot) ----
  const int aBase = (hl * 128 + wm * 64 + l31) * 16;   // + s*4096 (+512 fb=1)

  f32x16 acc[2][2];
#pragma unroll
  for (int i = 0; i < 2; ++i)
#pragma unroll
    for (int j = 0; j < 2; ++j)
#pragma unroll
      for (int r = 0; r < 16; ++r) acc[i][j][r] = 0.f;

  // ---- A-gen state ----
  float bb[16], ff[16];
  float4 xh[4];
  int eslot = 0, cchunk = 0;                  // eslot = slot of NEXT emitA call
#pragma unroll
  for (int q = 0; q < 4; ++q) xh[q] = *(const float4*)(xg + q * 4);   // chunk 0

  auto loadB = [&](short8 (&bv)[4][2], int tt) {
    const char* WbT = Wb + (size_t)tt * 65536;
#pragma unroll
    for (int s = 0; s < 4; ++s) {
      bv[s][0] = *(const short8*)(WbT + boff[s][0]);
      bv[s][1] = *(const short8*)(WbT + boff[s][1]);
    }
  };

  // emit the next A K-step slice (sequential eslot/recurrence state)
  auto emitA = [&](char* pDst) {
    unsigned int w[8];
    if (eslot == 0) {                         // A = x (current chunk), init basis
      float f[16];
#pragma unroll
      for (int q = 0; q < 4; ++q) {
        f[q*4+0] = xh[q].x; f[q*4+1] = xh[q].y; f[q*4+2] = xh[q].z; f[q*4+3] = xh[q].w;
      }
#pragma unroll
      for (int j = 0; j < 8; ++j) CVTPK(w[j], f[2*j], f[2*j+1]);
      *(u32x4*)(pDst + aoff0) = (u32x4){w[0], w[1], w[2], w[3]};
      *(u32x4*)(pDst + aoff1) = (u32x4){w[4], w[5], w[6], w[7]};
#pragma unroll
      for (int j = 0; j < 16; ++j) {
        float u = fmaf(f[j], 1.375f, 5.5f);
        bb[j] = exp2f(-0.72134752044448170f * u * u);
        ff[j] = exp2f(fmaf(u, 1.44269504088896340f, -0.72134752044448170f));
      }
    } else {                                  // A = basis, advance recurrence
#pragma unroll
      for (int j = 0; j < 8; ++j) CVTPK(w[j], bb[2*j], bb[2*j+1]);
      *(u32x4*)(pDst + aoff0) = (u32x4){w[0], w[1], w[2], w[3]};
      *(u32x4*)(pDst + aoff1) = (u32x4){w[4], w[5], w[6], w[7]};
#pragma unroll
      for (int j = 0; j < 16; ++j) {
        bb[j] *= ff[j];
        ff[j] *= 0.36787944117144233f;        // e^-1
      }
    }
    if (eslot == 1 && cchunk < 7) {           // preload next x chunk (~12 steps early)
      ++cchunk;
      const float* xn = xg + (size_t)cchunk * 64;
#pragma unroll
      for (int q = 0; q < 4; ++q) xh[q] = *(const float4*)(xn + q * 4);
    }
    eslot = (eslot == 12) ? 0 : eslot + 1;
  };

#define MFMA_CLUSTER(AV, BV)                                                         \
  _Pragma("unroll")                                                                  \
  for (int s = 0; s < 4; ++s) {                                                      \
    acc[0][0] = __builtin_amdgcn_mfma_f32_32x32x16_bf16(AV[s][0], BV[s][0], acc[0][0], 0, 0, 0); \
    acc[0][1] = __builtin_amdgcn_mfma_f32_32x32x16_bf16(AV[s][0], BV[s][1], acc[0][1], 0, 0, 0); \
    acc[1][0] = __builtin_amdgcn_mfma_f32_32x32x16_bf16(AV[s][1], BV[s][0], acc[1][0], 0, 0, 0); \
    acc[1][1] = __builtin_amdgcn_mfma_f32_32x32x16_bf16(AV[s][1], BV[s][1], acc[1][1], 0, 0, 0); \
  }

  // one K-step, no barrier: prefetch bvN(t+1), read A slot (t%4), emit A(t+2)
  // into slot ((t+2)%4), MFMA with bvC (loaded previous step).
  auto stepBody = [&](int tt, int rdOff, int emOff,
                      short8 (&bvC)[4][2], short8 (&bvN)[4][2]) {
    if (tt < NSTEP - 1) loadB(bvN, tt + 1);
    const char* pA = (const char*)Asw + rdOff;
    short8 av[4][2];
#pragma unroll
    for (int s = 0; s < 4; ++s) {
      av[s][0] = *(const short8*)(pA + aBase + s * 4096);
      av[s][1] = *(const short8*)(pA + aBase + s * 4096 + 512);
    }
    if (tt < NSTEP - 2) emitA((char*)Asw + emOff);
    MFMA_CLUSTER(av, bvC);
  };

  // ================= prologue: emit A(0)->slot0, A(1)->slot1; load B(0) =================
  short8 bvA[4][2], bvB[4][2];
  emitA((char*)Asw);                          // A(0), slot 0 (inits bb/ff)
  emitA((char*)Asw + 16384);                  // A(1), slot 1
  loadB(bvA, 0);
  asm volatile("s_waitcnt lgkmcnt(0)" ::: "memory");
  __builtin_amdgcn_s_barrier();

  // ============ main loop: 2 steps per barrier window, 2 windows/iter ============
#pragma unroll 1
  for (int t = 0; t < NSTEP; t += 4) {
    // window 1: steps t, t+1 (read slots 0,1; emit slots 2,3)
    stepBody(t,     0,     32768, bvA, bvB);
    stepBody(t + 1, 16384, 49152, bvB, bvA);
    asm volatile("s_waitcnt lgkmcnt(0)" ::: "memory");
    __builtin_amdgcn_s_barrier();
    // window 2: steps t+2, t+3 (read slots 2,3; emit slots 0,1)
    stepBody(t + 2, 32768, 0,     bvA, bvB);
    stepBody(t + 3, 49152, 16384, bvB, bvA);
    asm volatile("s_waitcnt lgkmcnt(0)" ::: "memory");
    __builtin_amdgcn_s_barrier();
  }

  // ---- epilogue: D col(o) = lane&31, row(b) = (r&3)+8*(r>>2)+4*hl ----
  float bvv[2];
#pragma unroll
  for (int fo = 0; fo < 2; ++fo) bvv[fo] = bias[N0 + wn * 64 + fo * 32 + l31];
  const int rbase = 4 * hl;
#pragma unroll
  for (int fb = 0; fb < 2; ++fb) {
#pragma unroll
    for (int fo = 0; fo < 2; ++fo) {
      const size_t cix = (size_t)(N0 + wn * 64 + fo * 32 + l31);
#pragma unroll
      for (int r = 0; r < 16; ++r) {
        int row = M0 + wm * 64 + fb * 32 + (r & 3) + 8 * (r >> 2) + rbase;
        out[(size_t)row * N_DIM + cix] = acc[fb][fo][r] + bvv[fo];
      }
    }
  }
}

extern "C" void kernel_launch(void* const* d_in, const int* in_sizes, int n_in,
                              void* d_out, int out_size, void* d_ws, size_t ws_size,
                              hipStream_t stream) {
  const float* x      = (const float*)d_in[0];
  const float* coeff  = (const float*)d_in[1];
  const float* base_w = (const float*)d_in[2];
  const float* base_b = (const float*)d_in[3];
  // d_in[4] (centers) is implied by u = x*1.375 + 5.5 (exact)
  unsigned short* Wb2 = (unsigned short*)d_ws;   // needs 6,815,744 B

  prep_w<<<3328, 256, 0, stream>>>(coeff, base_w, Wb2);
  kan_gemm<<<256, 512, 0, stream>>>(x, Wb2, base_b, (float*)d_out);
}